// Round 13
// baseline (146.134 us; speedup 1.0000x reference)
//
#include <hip/hip_runtime.h>
#include <math.h>

typedef _Float16 f16;
typedef __fp16 h16x2 __attribute__((ext_vector_type(2)));
typedef _Float16 f16x4 __attribute__((ext_vector_type(4)));
typedef _Float16 f16x8 __attribute__((ext_vector_type(8)));
typedef float f32x4 __attribute__((ext_vector_type(4)));
typedef float f32x16 __attribute__((ext_vector_type(16)));
typedef unsigned int u32;

#define D_MODEL 1024
#define NHEADS 16
#define DHEAD 64
#define LQ 2048
#define LKK 2048
#define BB 2
#define LOG2E 1.4426950408889634f

static __device__ __forceinline__ void gload16(const void* g, void* l) {
  __builtin_amdgcn_global_load_lds(
      (const __attribute__((address_space(1))) u32*)g,
      (__attribute__((address_space(3))) u32*)l, 16, 0, 0);
}
static __device__ __forceinline__ float ex2(float x) {
  float r;
  asm volatile("v_exp_f32 %0, %1\n\ts_nop 0" : "=v"(r) : "v"(x));
  return r;
}
static __device__ __forceinline__ u32 pkr(float a, float b) {
  union { h16x2 h; u32 u; } c;
  c.h = __builtin_amdgcn_cvt_pkrtz(a, b);
  return c.u;
}
static __device__ __forceinline__ float fmax3(float a, float b, float c) {
  return fmaxf(fmaxf(a, b), c);  // clang fuses to v_max3_f32
}
#define MFMA16(a, b, c) __builtin_amdgcn_mfma_f32_16x16x32_f16(a, b, c, 0, 0, 0)
#define MFMA32(a, b, c) __builtin_amdgcn_mfma_f32_32x32x16_f16(a, b, c, 0, 0, 0)

// ---------------- W convert + prep (mask detect/convert, bias table) ----------------
__global__ void k_cvtw_prep(const float* Wq, const float* Wk, const float* Wv, const float* Wo,
                            f16* W16, const void* msk, const float* __restrict__ rel,
                            float* __restrict__ biasT, unsigned char* __restrict__ m8) {
  const int blk = blockIdx.x;
  const int t = threadIdx.x;
  if (blk < 4096) {  // W fp32->fp16: 1M float4
    int i = blk * 256 + t;
    int which = i >> 18, off = i & 262143;
    const float* s = which == 0 ? Wq : (which == 1 ? Wk : (which == 2 ? Wv : Wo));
    float4 x = ((const float4*)s)[off];
    f16x4 o; o[0] = (f16)x.x; o[1] = (f16)x.y; o[2] = (f16)x.z; o[3] = (f16)x.w;
    ((f16x4*)(W16 + (size_t)which * 1048576))[off] = o;
    return;
  }
  if (blk == 4096) {  // mask dtype detect + convert to u8
    __shared__ int o1s, o2s;
    if (t == 0) { o1s = 0; o2s = 0; }
    __syncthreads();
    const unsigned char* raw = (const unsigned char*)msk;
    int o1 = 0, o2 = 0;
    for (int i = t; i < BB * LKK; i += 256) {
      unsigned char vv = raw[i];
      if ((i & 3) && vv) o1 = 1;
      if (((i & 3) == 2) && vv == 0x80u) o2 = 1;
    }
    if (o1) atomicOr(&o1s, 1);
    if (o2) atomicOr(&o2s, 1);
    __syncthreads();
    const int f = o1s ? (o2s ? 2 : 1) : 0;  // 0=int32, 1=bool, 2=f32
    for (int i = t; i < BB * LKK; i += 256) {
      unsigned char vv;
      if (f == 0)      vv = (((const int*)msk)[i] != 0);
      else if (f == 1) vv = (((const unsigned char*)msk)[i] != 0);
      else             vv = (((const float*)msk)[i] != 0.0f);
      m8[i] = vv;
    }
    return;
  }
  // blk == 4097: bias table, pre-scaled by log2e
  for (int n = t; n < 2048; n += 256) {
    int bucket;
    if (n < 16) bucket = n;
    else {
      float tt = logf((float)n / 16.0f + 1e-9f);  // exact jax op order
      tt = tt / 2.0794415416798357f;
      tt = tt * 16.0f;
      bucket = 16 + (int)tt;
      if (bucket > 31) bucket = 31;
    }
    for (int h = 0; h < NHEADS; ++h)
      biasT[h * 2048 + n] = rel[bucket * NHEADS + h] * LOG2E;
  }
}

// ---------------- QKV GEMM: C = A_f32[4096,1024] * B_f16[1024,1024]^T, tile 128x128 ------
// A staged as RAW FP32 via global_load_lds (async, no VGPR round-trip); converted to f16
// (RTE) during fragment load. A rows = 128 B -> XOR-swizzled (pre-swizzled global source,
// swizzled frag-read address). B f16 as before. Double-buffered, one barrier per K-step.
// EPI 0: f16 scatter [B,H,L,64].  EPI 2: f16 V^T [B,H,64,L].
template <int EPI>
static __device__ __forceinline__ void gemm_core_a32(const float* __restrict__ A,
                                                     const f16* __restrict__ Bm,
                                                     void* __restrict__ C,
                                                     float* sA32, f16* sB) {
  const int t = threadIdx.x;
  const int w = t >> 6, lane = t & 63;
  const int lg = lane >> 4, lc = lane & 15;
  const int wr = w >> 1, wc = w & 1;
  const long row0 = (long)blockIdx.x * 128;
  const long col0 = (long)blockIdx.y * 128;
  f32x4 acc[4][4] = {};

  auto STAGEA = [&](int kk, int buf) {
#pragma unroll
    for (int it = 0; it < 4; ++it) {
      int ch = t + it * 256;          // 1024 chunks of 16B over [128 rows][8 granules]
      int r = ch >> 3, g = ch & 7;
      gload16(A + (row0 + r) * 1024 + kk * 32 + ((g ^ (r & 7)) * 4),
              (char*)sA32 + buf * 16384 + ch * 16);
    }
  };
  auto STAGEB = [&](int kk, int buf) {
#pragma unroll
    for (int it = 0; it < 2; ++it) {
      int ch = t + it * 256;
      int r = ch >> 2, kq = ch & 3;
      gload16(Bm + (col0 + r) * 1024 + kk * 32 + kq * 8, (char*)sB + buf * 8192 + ch * 16);
    }
  };
  auto COMPUTE = [&](int buf) {
    f16x8 af[4], bf[4];
#pragma unroll
    for (int i = 0; i < 4; ++i) {
      int row = wr * 64 + i * 16 + lc;
      const char* rp = (const char*)sA32 + buf * 16384 + row * 128;
      f32x4 v0 = *(const f32x4*)(rp + (((lg * 2 + 0) ^ (row & 7)) * 16));
      f32x4 v1 = *(const f32x4*)(rp + (((lg * 2 + 1) ^ (row & 7)) * 16));
      f16x8 o;
      o[0] = (f16)v0[0]; o[1] = (f16)v0[1]; o[2] = (f16)v0[2]; o[3] = (f16)v0[3];
      o[4] = (f16)v1[0]; o[5] = (f16)v1[1]; o[6] = (f16)v1[2]; o[7] = (f16)v1[3];
      af[i] = o;
    }
#pragma unroll
    for (int j = 0; j < 4; ++j)
      bf[j] = *(const f16x8*)&sB[buf * 4096 + (wc * 64 + j * 16 + lc) * 32 + lg * 8];
#pragma unroll
    for (int i = 0; i < 4; ++i)
#pragma unroll
      for (int j = 0; j < 4; ++j)
        acc[i][j] = MFMA16(af[i], bf[j], acc[i][j]);
  };

  STAGEA(0, 0);
  STAGEB(0, 0);
  __syncthreads();

  for (int kk = 0; kk < 32; ++kk) {
    const int cur = kk & 1;
    if (kk < 31) {  // issue next-step DMA before compute; latency hides under MFMAs
      STAGEA(kk + 1, cur ^ 1);
      STAGEB(kk + 1, cur ^ 1);
    }
    COMPUTE(cur);
    __syncthreads();
  }

#pragma unroll
  for (int i = 0; i < 4; ++i)
#pragma unroll
    for (int j = 0; j < 4; ++j) {
      const long rowb = row0 + wr * 64 + i * 16 + lg * 4;
      const long col = col0 + wc * 64 + j * 16 + lc;
      if (EPI == 2) {  // V^T: [b,h,d,l] with f16x4 over l
        long b = rowb >> 11, l0 = rowb & 2047;
        long h = col >> 6, d = col & 63;
        f16x4 ov;
#pragma unroll
        for (int r = 0; r < 4; ++r) ov[r] = (f16)acc[i][j][r];
        *(f16x4*)((f16*)C + (((b * NHEADS + h) * DHEAD + d) * (long)LKK + l0)) = ov;
      } else {
#pragma unroll
        for (int r = 0; r < 4; ++r) {
          long row = rowb + r;
          long b = row >> 11, l = row & 2047;
          long h = col >> 6, d = col & 63;
          ((f16*)C)[(((b * NHEADS + h) * LQ) + l) * DHEAD + d] = (f16)acc[i][j][r];
        }
      }
    }
}

__global__ void __launch_bounds__(256, 3)
k_gemm_qkv(const float* __restrict__ q, const float* __restrict__ k, const float* __restrict__ v,
           const f16* __restrict__ W16, f16* __restrict__ QHp, f16* __restrict__ KHp,
           f16* __restrict__ VTp) {
  __shared__ __align__(16) float sA32[8192];  // 2 bufs x 4096 fp32 = 32 KB
  __shared__ __align__(16) f16 sB[8192];      // 2 bufs x 4096 f16  = 16 KB
  const int z = blockIdx.z;
  if (z == 2) {
    gemm_core_a32<2>(v, W16 + 2 * 1048576, VTp, sA32, sB);
  } else {
    const float* A = z == 0 ? q : k;
    f16* C = z == 0 ? QHp : KHp;
    gemm_core_a32<0>(A, W16 + (size_t)z * 1048576, C, sA32, sB);
  }
}

// ---------------- O GEMM: f16 A, fp32 out, tile 128x64 (2 blocks/CU) ----------------
__global__ void __launch_bounds__(256, 2)
k_gemm_o(const f16* __restrict__ A, const f16* __restrict__ Bm, float* __restrict__ C) {
  __shared__ __align__(16) f16 smem[2 * 4096 + 2 * 2048];  // 24 KB
  f16* sA = smem;
  f16* sB = smem + 8192;
  const int t = threadIdx.x;
  const int w = t >> 6, lane = t & 63;
  const int lg = lane >> 4, lc = lane & 15;
  const int wr = w >> 1, wc = w & 1;
  const long row0 = (long)blockIdx.x * 128;
  const long col0 = (long)blockIdx.y * 64;
  f32x4 acc[4][2] = {};

  const int rA0 = t >> 2, kA0 = t & 3;
  const int rA1 = (t + 256) >> 2;

  auto STAGEA = [&](int kk, int buf) {
    gload16(A + (row0 + rA0) * 1024 + kk * 32 + kA0 * 8, (char*)sA + buf * 8192 + t * 16);
    gload16(A + (row0 + rA1) * 1024 + kk * 32 + kA0 * 8,
            (char*)sA + buf * 8192 + (t + 256) * 16);
  };
  auto STAGEB = [&](int kk, int buf) {
    int r = t >> 2, kq = t & 3;
    gload16(Bm + (col0 + r) * 1024 + kk * 32 + kq * 8, (char*)sB + buf * 4096 + t * 16);
  };
  auto COMPUTE = [&](int buf) {
    f16x8 af[4], bf[2];
#pragma unroll
    for (int i = 0; i < 4; ++i)
      af[i] = *(const f16x8*)&sA[buf * 4096 + (wr * 64 + i * 16 + lc) * 32 + lg * 8];
#pragma unroll
    for (int j = 0; j < 2; ++j)
      bf[j] = *(const f16x8*)&sB[buf * 2048 + (wc * 32 + j * 16 + lc) * 32 + lg * 8];
#pragma unroll
    for (int i = 0; i < 4; ++i)
#pragma unroll
      for (int j = 0; j < 2; ++j)
        acc[i][j] = MFMA16(af[i], bf[j], acc[i][j]);
  };

  STAGEA(0, 0);
  STAGEB(0, 0);
  __syncthreads();
  for (int kk = 0; kk < 32; ++kk) {
    const int cur = kk & 1;
    if (kk < 31) { STAGEA(kk + 1, cur ^ 1); STAGEB(kk + 1, cur ^ 1); }
    COMPUTE(cur);
    __syncthreads();
  }
#pragma unroll
  for (int i = 0; i < 4; ++i)
#pragma unroll
    for (int j = 0; j < 2; ++j) {
      const long rowb = row0 + wr * 64 + i * 16 + lg * 4;
      const long col = col0 + wc * 32 + j * 16 + lc;
#pragma unroll
      for (int r = 0; r < 4; ++r)
        C[(rowb + r) * 1024 + col] = acc[i][j][r];
    }
}

// ---------------- flash attention (R4-proven 68.3µs version) ----------------
// 4 warps/block, 32 q-rows/warp. Grid 512 = 16 qchunks x 32 (b,h), XCD-clustered.
__global__ void __launch_bounds__(256, 2)
k_attn(const f16* __restrict__ QH, const f16* __restrict__ KH, const f16* __restrict__ VT,
       const float* __restrict__ BIASg, const unsigned char* __restrict__ M8,
       f16* __restrict__ O16) {
  __shared__ __align__(16) f16 sK[2][64 * 64];   // K tiles, XOR-swizzled rows
  __shared__ __align__(16) f16 sVT[2][64 * 64];  // V^T tiles, XOR-swizzled rows
  __shared__ __align__(16) float sBias[4104];    // bias*log2e, padded for n<0
  __shared__ __align__(16) float sPen[2048];     // mask penalty (log2 domain)

  const int L = blockIdx.x;
  const int bh = (L & 7) * 4 + ((L >> 3) & 3);   // same-bh blocks -> same XCD
  const int qc = L >> 5;
  const int b = bh >> 4, h = bh & 15;
  const int t = threadIdx.x, w = t >> 6, lane = t & 63;
  const int lq = lane & 31, hi = lane >> 5;
  const int q0w = qc * 128 + w * 32;
  const size_t base = (size_t)bh * LKK * DHEAD;

  for (int i = t; i < 4104; i += 256) {
    int n = i - 2052; n = n < 0 ? 0 : (n > 2047 ? 2047 : n);
    sBias[i] = BIASg[h * 2048 + n];
  }
  for (int i = t; i < 2048; i += 256)
    sPen[i] = M8[b * LKK + i] ? 0.0f : -3.0e9f;

  f16x8 qb[4];
  const f16* qrow = QH + base + (size_t)(q0w + lq) * DHEAD;
#pragma unroll
  for (int s = 0; s < 4; ++s)
    qb[s] = *(const f16x8*)(qrow + s * 16 + hi * 8);

  const int ch0 = t, ch1 = t + 256;
  const int r0 = ch0 >> 3, g0 = ((ch0 & 7) ^ (r0 & 7)) * 8;
  const int r1 = ch1 >> 3, g1 = ((ch1 & 7) ^ (r1 & 7)) * 8;
  const f16* Kb = KH + base;
  const f16* Vb = VT + base;

  auto STAGE = [&](int kt, int buf) {
    const int k0 = kt * 64;
    gload16(Kb + (size_t)(k0 + r0) * DHEAD + g0, (char*)&sK[buf][0] + ch0 * 16);
    gload16(Kb + (size_t)(k0 + r1) * DHEAD + g1, (char*)&sK[buf][0] + ch1 * 16);
    gload16(Vb + (size_t)r0 * LKK + k0 + g0, (char*)&sVT[buf][0] + ch0 * 16);
    gload16(Vb + (size_t)r1 * LKK + k0 + g1, (char*)&sVT[buf][0] + ch1 * 16);
  };

  float m_r = -1e30f;
  f32x16 oacc0 = {}, oacc1 = {}, oaccL = {};
  const float c1 = 0.125f * LOG2E;
  f16x8 ones;
#pragma unroll
  for (int e = 0; e < 8; ++e) ones[e] = (f16)1.0f;

  STAGE(0, 0);
  __syncthreads();

  for (int kt = 0; kt < 32; ++kt) {
    const int cur = kt & 1;
    if (kt < 31) STAGE(kt + 1, cur ^ 1);

    const char* sKb = (const char*)&sK[cur][0];
    f32x16 sa0 = {}, sa1 = {};
#pragma unroll
    for (int s = 0; s < 4; ++s) {
      f16x8 k0 = *(const f16x8*)(sKb + ((lq * 128 + s * 32 + hi * 16) ^ ((lq & 7) << 4)));
      f16x8 k1 = *(const f16x8*)(sKb + (((32 + lq) * 128 + s * 32 + hi * 16) ^ ((lq & 7) << 4)));
      sa0 = MFMA32(k0, qb[s], sa0);
      sa1 = MFMA32(k1, qb[s], sa1);
    }

    float p_[32];
#pragma unroll
    for (int r = 0; r < 16; ++r) { p_[r] = sa0[r]; p_[16 + r] = sa1[r]; }

#pragma unroll
    for (int u = 0; u < 8; ++u) {
      int tt = u >> 2, j = u & 3;
      int kbase = kt * 64 + tt * 32 + j * 8 + hi * 4;
      f32x4 pen4 = *(const f32x4*)&sPen[kbase];
      int bidx0 = (q0w + lq) - kbase + 2052;
#pragma unroll
      for (int e = 0; e < 4; ++e) {
        float bp = sBias[bidx0 - e] + pen4[e];
        int r = tt * 16 + j * 4 + e;
        p_[r] = p_[r] * c1 + bp;
      }
    }

    float mm[11];
#pragma unroll
    for (int r = 0; r < 10; ++r) mm[r] = fmax3(p_[3 * r], p_[3 * r + 1], p_[3 * r + 2]);
    mm[10] = fmaxf(p_[30], p_[31]);
    float a0 = fmax3(mm[0], mm[1], mm[2]);
    float a1 = fmax3(mm[3], mm[4], mm[5]);
    float a2 = fmax3(mm[6], mm[7], mm[8]);
    float a3 = fmax3(mm[9], mm[10], a0);
    float mx = fmax3(a1, a2, a3);
    mx = fmaxf(mx, __shfl_xor(mx, 32));

    if (__any(mx > m_r + 8.0f)) {
      float mnew = fmaxf(m_r, mx);
      float al = ex2(m_r - mnew);
      m_r = mnew;
#pragma unroll
      for (int r = 0; r < 16; ++r) { oacc0[r] *= al; oacc1[r] *= al; oaccL[r] *= al; }
    }

#pragma unroll
    for (int r = 0; r < 32; ++r) p_[r] = ex2(p_[r] - m_r);

    f16x8 pf[4];
#pragma unroll
    for (int sl = 0; sl < 4; ++sl) {
      int tt = sl >> 1, sp = sl & 1;
      int bA = tt * 16 + (2 * sp) * 4, bB = tt * 16 + (2 * sp + 1) * 4;
      u32 A0 = pkr(p_[bA], p_[bA + 1]);
      u32 A1 = pkr(p_[bA + 2], p_[bA + 3]);
      u32 B0 = pkr(p_[bB], p_[bB + 1]);
      u32 B1 = pkr(p_[bB + 2], p_[bB + 3]);
      asm volatile("v_permlane32_swap_b32 %0, %1" : "+v"(A0), "+v"(B0));
      asm volatile("v_permlane32_swap_b32 %0, %1" : "+v"(A1), "+v"(B1));
      union { u32 u[4]; f16x8 v; } c;
      c.u[0] = A0; c.u[1] = A1; c.u[2] = B0; c.u[3] = B1;
      pf[sl] = c.v;
    }

    const char* sVb = (const char*)&sVT[cur][0];
#pragma unroll
    for (int sl = 0; sl < 4; ++sl) {
      int K0 = sl * 16;
      f16x8 v0 = *(const f16x8*)(sVb + ((lq * 128 + K0 * 2 + hi * 16) ^ ((lq & 7) << 4)));
      f16x8 v1 = *(const f16x8*)(sVb + (((32 + lq) * 128 + K0 * 2 + hi * 16) ^ ((lq & 7) << 4)));
      oacc0 = MFMA32(v0, pf[sl], oacc0);
      oacc1 = MFMA32(v1, pf[sl], oacc1);
      oaccL = MFMA32(ones, pf[sl], oaccL);
    }
    __syncthreads();
  }

  const float rinv = 1.0f / oaccL[0];
  const size_t orow = ((size_t)b * LQ + (q0w + lq)) * D_MODEL + h * DHEAD;
#pragma unroll
  for (int dh = 0; dh < 2; ++dh)
#pragma unroll
    for (int j = 0; j < 4; ++j) {
      int d0 = dh * 32 + j * 8 + hi * 4;
      f16x4 ov;
#pragma unroll
      for (int e = 0; e < 4; ++e) {
        float x = (dh ? oacc1[j * 4 + e] : oacc0[j * 4 + e]) * rinv;
        ov[e] = (f16)x;
      }
      *(f16x4*)(O16 + orow + d0) = ov;
    }
}

// ---------------- launch ----------------
// ws plan (41 MB): slab0 QHp, slab1 KHp, slab2 VTp, slab3 O16, slab4 W16, slab5 misc.
extern "C" void kernel_launch(void* const* d_in, const int* in_sizes, int n_in,
                              void* d_out, int out_size, void* d_ws, size_t ws_size,
                              hipStream_t stream) {
  (void)in_sizes; (void)n_in; (void)out_size; (void)ws_size;
  const float* q   = (const float*)d_in[0];
  const float* k   = (const float*)d_in[1];
  const float* v   = (const float*)d_in[2];
  const void*  msk = d_in[3];
  const float* Wq  = (const float*)d_in[4];
  const float* Wk  = (const float*)d_in[5];
  const float* Wv  = (const float*)d_in[6];
  const float* Wo  = (const float*)d_in[7];
  const float* rel = (const float*)d_in[8];

  char* ws = (char*)d_ws;
  const size_t SL = (size_t)8 << 20;
  f16* QHp = (f16*)(ws + 0 * SL);
  f16* KHp = (f16*)(ws + 1 * SL);
  f16* VTp = (f16*)(ws + 2 * SL);
  f16* O16 = (f16*)(ws + 3 * SL);
  f16* W16 = (f16*)(ws + 4 * SL);
  char* misc = ws + 5 * SL;
  float* BIAS = (float*)misc;
  unsigned char* M8 = (unsigned char*)(misc + (192 << 10));

  k_cvtw_prep<<<4098, 256, 0, stream>>>(Wq, Wk, Wv, Wo, W16, msk, rel, BIAS, M8);
  k_gemm_qkv<<<dim3(32, 8, 3), 256, 0, stream>>>(q, k, v, W16, QHp, KHp, VTp);
  k_attn<<<512, 256, 0, stream>>>(QHp, KHp, VTp, BIAS, M8, O16);
  k_gemm_o<<<dim3(32, 16), 256, 0, stream>>>(O16, W16 + 3 * 1048576, (float*)d_out);
}

// Round 14
// 142.631 us; speedup vs baseline: 1.0246x; 1.0246x over previous
//
#include <hip/hip_runtime.h>
#include <math.h>

typedef _Float16 f16;
typedef __fp16 h16x2 __attribute__((ext_vector_type(2)));
typedef _Float16 f16x4 __attribute__((ext_vector_type(4)));
typedef _Float16 f16x8 __attribute__((ext_vector_type(8)));
typedef float f32x4 __attribute__((ext_vector_type(4)));
typedef float f32x16 __attribute__((ext_vector_type(16)));
typedef unsigned int u32;

#define D_MODEL 1024
#define NHEADS 16
#define DHEAD 64
#define LQ 2048
#define LKK 2048
#define BB 2
#define LOG2E 1.4426950408889634f

static __device__ __forceinline__ void gload16(const void* g, void* l) {
  __builtin_amdgcn_global_load_lds(
      (const __attribute__((address_space(1))) u32*)g,
      (__attribute__((address_space(3))) u32*)l, 16, 0, 0);
}
static __device__ __forceinline__ float ex2(float x) {
  float r;
  asm volatile("v_exp_f32 %0, %1\n\ts_nop 0" : "=v"(r) : "v"(x));
  return r;
}
static __device__ __forceinline__ u32 pkr(float a, float b) {
  union { h16x2 h; u32 u; } c;
  c.h = __builtin_amdgcn_cvt_pkrtz(a, b);
  return c.u;
}
static __device__ __forceinline__ float fmax3(float a, float b, float c) {
  return fmaxf(fmaxf(a, b), c);  // clang fuses to v_max3_f32
}
#define MFMA16(a, b, c) __builtin_amdgcn_mfma_f32_16x16x32_f16(a, b, c, 0, 0, 0)
#define MFMA32(a, b, c) __builtin_amdgcn_mfma_f32_32x32x16_f16(a, b, c, 0, 0, 0)

// ---------------- W convert + prep (mask detect/convert, bias table) ----------------
__global__ void k_cvtw_prep(const float* Wq, const float* Wk, const float* Wv, const float* Wo,
                            f16* W16, const void* msk, const float* __restrict__ rel,
                            float* __restrict__ biasT, unsigned char* __restrict__ m8) {
  const int blk = blockIdx.x;
  const int t = threadIdx.x;
  if (blk < 4096) {  // W fp32->fp16: 1M float4
    int i = blk * 256 + t;
    int which = i >> 18, off = i & 262143;
    const float* s = which == 0 ? Wq : (which == 1 ? Wk : (which == 2 ? Wv : Wo));
    float4 x = ((const float4*)s)[off];
    f16x4 o; o[0] = (f16)x.x; o[1] = (f16)x.y; o[2] = (f16)x.z; o[3] = (f16)x.w;
    ((f16x4*)(W16 + (size_t)which * 1048576))[off] = o;
    return;
  }
  if (blk == 4096) {  // mask dtype detect + convert to u8
    __shared__ int o1s, o2s;
    if (t == 0) { o1s = 0; o2s = 0; }
    __syncthreads();
    const unsigned char* raw = (const unsigned char*)msk;
    int o1 = 0, o2 = 0;
    for (int i = t; i < BB * LKK; i += 256) {
      unsigned char vv = raw[i];
      if ((i & 3) && vv) o1 = 1;
      if (((i & 3) == 2) && vv == 0x80u) o2 = 1;
    }
    if (o1) atomicOr(&o1s, 1);
    if (o2) atomicOr(&o2s, 1);
    __syncthreads();
    const int f = o1s ? (o2s ? 2 : 1) : 0;  // 0=int32, 1=bool, 2=f32
    for (int i = t; i < BB * LKK; i += 256) {
      unsigned char vv;
      if (f == 0)      vv = (((const int*)msk)[i] != 0);
      else if (f == 1) vv = (((const unsigned char*)msk)[i] != 0);
      else             vv = (((const float*)msk)[i] != 0.0f);
      m8[i] = vv;
    }
    return;
  }
  // blk == 4097: bias table, pre-scaled by log2e
  for (int n = t; n < 2048; n += 256) {
    int bucket;
    if (n < 16) bucket = n;
    else {
      float tt = logf((float)n / 16.0f + 1e-9f);  // exact jax op order
      tt = tt / 2.0794415416798357f;
      tt = tt * 16.0f;
      bucket = 16 + (int)tt;
      if (bucket > 31) bucket = 31;
    }
    for (int h = 0; h < NHEADS; ++h)
      biasT[h * 2048 + n] = rel[bucket * NHEADS + h] * LOG2E;
  }
}

// ---------------- QKV GEMM: C = A_f32[4096,1024] * B_f16[1024,1024]^T, tile 128x128 ------
// A staged RAW FP32 via global_load_lds; f16-converted (RTE) during fragment load.
// XCD-locality: 1D grid 768; the 8 col-blocks sharing an A-row-tile get block IDs
// congruent mod 8 -> same XCD -> A re-reads hit that XCD's L2 instead of L3.
// EPI 0: f16 scatter [B,H,L,64].  EPI 2: f16 V^T [B,H,64,L].
template <int EPI>
static __device__ __forceinline__ void gemm_core_a32(const float* __restrict__ A,
                                                     const f16* __restrict__ Bm,
                                                     void* __restrict__ C,
                                                     float* sA32, f16* sB,
                                                     int xrow, int ycol) {
  const int t = threadIdx.x;
  const int w = t >> 6, lane = t & 63;
  const int lg = lane >> 4, lc = lane & 15;
  const int wr = w >> 1, wc = w & 1;
  const long row0 = (long)xrow * 128;
  const long col0 = (long)ycol * 128;
  f32x4 acc[4][4] = {};

  auto STAGEA = [&](int kk, int buf) {
#pragma unroll
    for (int it = 0; it < 4; ++it) {
      int ch = t + it * 256;          // 1024 chunks of 16B over [128 rows][8 granules]
      int r = ch >> 3, g = ch & 7;
      gload16(A + (row0 + r) * 1024 + kk * 32 + ((g ^ (r & 7)) * 4),
              (char*)sA32 + buf * 16384 + ch * 16);
    }
  };
  auto STAGEB = [&](int kk, int buf) {
#pragma unroll
    for (int it = 0; it < 2; ++it) {
      int ch = t + it * 256;
      int r = ch >> 2, kq = ch & 3;
      gload16(Bm + (col0 + r) * 1024 + kk * 32 + kq * 8, (char*)sB + buf * 8192 + ch * 16);
    }
  };
  auto COMPUTE = [&](int buf) {
    f16x8 af[4], bf[4];
#pragma unroll
    for (int i = 0; i < 4; ++i) {
      int row = wr * 64 + i * 16 + lc;
      const char* rp = (const char*)sA32 + buf * 16384 + row * 128;
      f32x4 v0 = *(const f32x4*)(rp + (((lg * 2 + 0) ^ (row & 7)) * 16));
      f32x4 v1 = *(const f32x4*)(rp + (((lg * 2 + 1) ^ (row & 7)) * 16));
      f16x8 o;
      o[0] = (f16)v0[0]; o[1] = (f16)v0[1]; o[2] = (f16)v0[2]; o[3] = (f16)v0[3];
      o[4] = (f16)v1[0]; o[5] = (f16)v1[1]; o[6] = (f16)v1[2]; o[7] = (f16)v1[3];
      af[i] = o;
    }
#pragma unroll
    for (int j = 0; j < 4; ++j)
      bf[j] = *(const f16x8*)&sB[buf * 4096 + (wc * 64 + j * 16 + lc) * 32 + lg * 8];
#pragma unroll
    for (int i = 0; i < 4; ++i)
#pragma unroll
      for (int j = 0; j < 4; ++j)
        acc[i][j] = MFMA16(af[i], bf[j], acc[i][j]);
  };

  STAGEA(0, 0);
  STAGEB(0, 0);
  __syncthreads();

  for (int kk = 0; kk < 32; ++kk) {
    const int cur = kk & 1;
    if (kk < 31) {
      STAGEA(kk + 1, cur ^ 1);
      STAGEB(kk + 1, cur ^ 1);
    }
    COMPUTE(cur);
    __syncthreads();
  }

#pragma unroll
  for (int i = 0; i < 4; ++i)
#pragma unroll
    for (int j = 0; j < 4; ++j) {
      const long rowb = row0 + wr * 64 + i * 16 + lg * 4;
      const long col = col0 + wc * 64 + j * 16 + lc;
      if (EPI == 2) {  // V^T: [b,h,d,l] with f16x4 over l
        long b = rowb >> 11, l0 = rowb & 2047;
        long h = col >> 6, d = col & 63;
        f16x4 ov;
#pragma unroll
        for (int r = 0; r < 4; ++r) ov[r] = (f16)acc[i][j][r];
        *(f16x4*)((f16*)C + (((b * NHEADS + h) * DHEAD + d) * (long)LKK + l0)) = ov;
      } else {
#pragma unroll
        for (int r = 0; r < 4; ++r) {
          long row = rowb + r;
          long b = row >> 11, l = row & 2047;
          long h = col >> 6, d = col & 63;
          ((f16*)C)[(((b * NHEADS + h) * LQ) + l) * DHEAD + d] = (f16)acc[i][j][r];
        }
      }
    }
}

__global__ void __launch_bounds__(256, 3)
k_gemm_qkv(const float* __restrict__ q, const float* __restrict__ k, const float* __restrict__ v,
           const f16* __restrict__ W16, f16* __restrict__ QHp, f16* __restrict__ KHp,
           f16* __restrict__ VTp) {
  __shared__ __align__(16) float sA32[8192];  // 2 bufs x 4096 fp32 = 32 KB
  __shared__ __align__(16) f16 sB[8192];      // 2 bufs x 4096 f16  = 16 KB
  // XCD-locality decode: id = rnd*64 + ycol*8 + c; row-group g = rnd*8 + c (z-major)
  const int bid = blockIdx.x;
  const int rnd = bid >> 6;            // 0..11
  const int within = bid & 63;
  const int ycol = within >> 3;        // 0..7
  const int c = within & 7;
  const int g = rnd * 8 + c;           // 0..95
  const int z = g >> 5;                // 0..2  (z-major keeps W_z coherent per round)
  const int xrow = g & 31;             // 0..31
  if (z == 2) {
    gemm_core_a32<2>(v, W16 + 2 * 1048576, VTp, sA32, sB, xrow, ycol);
  } else {
    const float* A = z == 0 ? q : k;
    f16* C = z == 0 ? QHp : KHp;
    gemm_core_a32<0>(A, W16 + (size_t)z * 1048576, C, sA32, sB, xrow, ycol);
  }
}

// ---------------- O GEMM: f16 A, fp32 out, tile 128x64, XCD-locality swizzled ----------------
__global__ void __launch_bounds__(256, 2)
k_gemm_o(const f16* __restrict__ A, const f16* __restrict__ Bm, float* __restrict__ C) {
  __shared__ __align__(16) f16 smem[2 * 4096 + 2 * 2048];  // 24 KB
  f16* sA = smem;
  f16* sB = smem + 8192;
  const int t = threadIdx.x;
  const int w = t >> 6, lane = t & 63;
  const int lg = lane >> 4, lc = lane & 15;
  const int wr = w >> 1, wc = w & 1;
  // XCD-locality decode: 512 blocks; 16 col-blocks per A-row-tile share an XCD
  const int bid = blockIdx.x;
  const int rnd = bid >> 7;            // 0..3
  const int within = bid & 127;
  const int ycol = within >> 3;        // 0..15
  const int c = within & 7;
  const int xrow = rnd * 8 + c;        // 0..31
  const long row0 = (long)xrow * 128;
  const long col0 = (long)ycol * 64;
  f32x4 acc[4][2] = {};

  const int rA0 = t >> 2, kA0 = t & 3;
  const int rA1 = (t + 256) >> 2;

  auto STAGEA = [&](int kk, int buf) {
    gload16(A + (row0 + rA0) * 1024 + kk * 32 + kA0 * 8, (char*)sA + buf * 8192 + t * 16);
    gload16(A + (row0 + rA1) * 1024 + kk * 32 + kA0 * 8,
            (char*)sA + buf * 8192 + (t + 256) * 16);
  };
  auto STAGEB = [&](int kk, int buf) {
    int r = t >> 2, kq = t & 3;
    gload16(Bm + (col0 + r) * 1024 + kk * 32 + kq * 8, (char*)sB + buf * 4096 + t * 16);
  };
  auto COMPUTE = [&](int buf) {
    f16x8 af[4], bf[2];
#pragma unroll
    for (int i = 0; i < 4; ++i)
      af[i] = *(const f16x8*)&sA[buf * 4096 + (wr * 64 + i * 16 + lc) * 32 + lg * 8];
#pragma unroll
    for (int j = 0; j < 2; ++j)
      bf[j] = *(const f16x8*)&sB[buf * 2048 + (wc * 32 + j * 16 + lc) * 32 + lg * 8];
#pragma unroll
    for (int i = 0; i < 4; ++i)
#pragma unroll
      for (int j = 0; j < 2; ++j)
        acc[i][j] = MFMA16(af[i], bf[j], acc[i][j]);
  };

  STAGEA(0, 0);
  STAGEB(0, 0);
  __syncthreads();
  for (int kk = 0; kk < 32; ++kk) {
    const int cur = kk & 1;
    if (kk < 31) { STAGEA(kk + 1, cur ^ 1); STAGEB(kk + 1, cur ^ 1); }
    COMPUTE(cur);
    __syncthreads();
  }
#pragma unroll
  for (int i = 0; i < 4; ++i)
#pragma unroll
    for (int j = 0; j < 2; ++j) {
      const long rowb = row0 + wr * 64 + i * 16 + lg * 4;
      const long col = col0 + wc * 32 + j * 16 + lc;
#pragma unroll
      for (int r = 0; r < 4; ++r)
        C[(rowb + r) * 1024 + col] = acc[i][j][r];
    }
}

// ---------------- flash attention (R4-proven 68.3µs version) ----------------
// 4 warps/block, 32 q-rows/warp. Grid 512 = 16 qchunks x 32 (b,h), XCD-clustered.
__global__ void __launch_bounds__(256, 2)
k_attn(const f16* __restrict__ QH, const f16* __restrict__ KH, const f16* __restrict__ VT,
       const float* __restrict__ BIASg, const unsigned char* __restrict__ M8,
       f16* __restrict__ O16) {
  __shared__ __align__(16) f16 sK[2][64 * 64];   // K tiles, XOR-swizzled rows
  __shared__ __align__(16) f16 sVT[2][64 * 64];  // V^T tiles, XOR-swizzled rows
  __shared__ __align__(16) float sBias[4104];    // bias*log2e, padded for n<0
  __shared__ __align__(16) float sPen[2048];     // mask penalty (log2 domain)

  const int L = blockIdx.x;
  const int bh = (L & 7) * 4 + ((L >> 3) & 3);   // same-bh blocks -> same XCD
  const int qc = L >> 5;
  const int b = bh >> 4, h = bh & 15;
  const int t = threadIdx.x, w = t >> 6, lane = t & 63;
  const int lq = lane & 31, hi = lane >> 5;
  const int q0w = qc * 128 + w * 32;
  const size_t base = (size_t)bh * LKK * DHEAD;

  for (int i = t; i < 4104; i += 256) {
    int n = i - 2052; n = n < 0 ? 0 : (n > 2047 ? 2047 : n);
    sBias[i] = BIASg[h * 2048 + n];
  }
  for (int i = t; i < 2048; i += 256)
    sPen[i] = M8[b * LKK + i] ? 0.0f : -3.0e9f;

  f16x8 qb[4];
  const f16* qrow = QH + base + (size_t)(q0w + lq) * DHEAD;
#pragma unroll
  for (int s = 0; s < 4; ++s)
    qb[s] = *(const f16x8*)(qrow + s * 16 + hi * 8);

  const int ch0 = t, ch1 = t + 256;
  const int r0 = ch0 >> 3, g0 = ((ch0 & 7) ^ (r0 & 7)) * 8;
  const int r1 = ch1 >> 3, g1 = ((ch1 & 7) ^ (r1 & 7)) * 8;
  const f16* Kb = KH + base;
  const f16* Vb = VT + base;

  auto STAGE = [&](int kt, int buf) {
    const int k0 = kt * 64;
    gload16(Kb + (size_t)(k0 + r0) * DHEAD + g0, (char*)&sK[buf][0] + ch0 * 16);
    gload16(Kb + (size_t)(k0 + r1) * DHEAD + g1, (char*)&sK[buf][0] + ch1 * 16);
    gload16(Vb + (size_t)r0 * LKK + k0 + g0, (char*)&sVT[buf][0] + ch0 * 16);
    gload16(Vb + (size_t)r1 * LKK + k0 + g1, (char*)&sVT[buf][0] + ch1 * 16);
  };

  float m_r = -1e30f;
  f32x16 oacc0 = {}, oacc1 = {}, oaccL = {};
  const float c1 = 0.125f * LOG2E;
  f16x8 ones;
#pragma unroll
  for (int e = 0; e < 8; ++e) ones[e] = (f16)1.0f;

  STAGE(0, 0);
  __syncthreads();

  for (int kt = 0; kt < 32; ++kt) {
    const int cur = kt & 1;
    if (kt < 31) STAGE(kt + 1, cur ^ 1);

    const char* sKb = (const char*)&sK[cur][0];
    f32x16 sa0 = {}, sa1 = {};
#pragma unroll
    for (int s = 0; s < 4; ++s) {
      f16x8 k0 = *(const f16x8*)(sKb + ((lq * 128 + s * 32 + hi * 16) ^ ((lq & 7) << 4)));
      f16x8 k1 = *(const f16x8*)(sKb + (((32 + lq) * 128 + s * 32 + hi * 16) ^ ((lq & 7) << 4)));
      sa0 = MFMA32(k0, qb[s], sa0);
      sa1 = MFMA32(k1, qb[s], sa1);
    }

    float p_[32];
#pragma unroll
    for (int r = 0; r < 16; ++r) { p_[r] = sa0[r]; p_[16 + r] = sa1[r]; }

#pragma unroll
    for (int u = 0; u < 8; ++u) {
      int tt = u >> 2, j = u & 3;
      int kbase = kt * 64 + tt * 32 + j * 8 + hi * 4;
      f32x4 pen4 = *(const f32x4*)&sPen[kbase];
      int bidx0 = (q0w + lq) - kbase + 2052;
#pragma unroll
      for (int e = 0; e < 4; ++e) {
        float bp = sBias[bidx0 - e] + pen4[e];
        int r = tt * 16 + j * 4 + e;
        p_[r] = p_[r] * c1 + bp;
      }
    }

    float mm[11];
#pragma unroll
    for (int r = 0; r < 10; ++r) mm[r] = fmax3(p_[3 * r], p_[3 * r + 1], p_[3 * r + 2]);
    mm[10] = fmaxf(p_[30], p_[31]);
    float a0 = fmax3(mm[0], mm[1], mm[2]);
    float a1 = fmax3(mm[3], mm[4], mm[5]);
    float a2 = fmax3(mm[6], mm[7], mm[8]);
    float a3 = fmax3(mm[9], mm[10], a0);
    float mx = fmax3(a1, a2, a3);
    mx = fmaxf(mx, __shfl_xor(mx, 32));

    if (__any(mx > m_r + 8.0f)) {
      float mnew = fmaxf(m_r, mx);
      float al = ex2(m_r - mnew);
      m_r = mnew;
#pragma unroll
      for (int r = 0; r < 16; ++r) { oacc0[r] *= al; oacc1[r] *= al; oaccL[r] *= al; }
    }

#pragma unroll
    for (int r = 0; r < 32; ++r) p_[r] = ex2(p_[r] - m_r);

    f16x8 pf[4];
#pragma unroll
    for (int sl = 0; sl < 4; ++sl) {
      int tt = sl >> 1, sp = sl & 1;
      int bA = tt * 16 + (2 * sp) * 4, bB = tt * 16 + (2 * sp + 1) * 4;
      u32 A0 = pkr(p_[bA], p_[bA + 1]);
      u32 A1 = pkr(p_[bA + 2], p_[bA + 3]);
      u32 B0 = pkr(p_[bB], p_[bB + 1]);
      u32 B1 = pkr(p_[bB + 2], p_[bB + 3]);
      asm volatile("v_permlane32_swap_b32 %0, %1" : "+v"(A0), "+v"(B0));
      asm volatile("v_permlane32_swap_b32 %0, %1" : "+v"(A1), "+v"(B1));
      union { u32 u[4]; f16x8 v; } c;
      c.u[0] = A0; c.u[1] = A1; c.u[2] = B0; c.u[3] = B1;
      pf[sl] = c.v;
    }

    const char* sVb = (const char*)&sVT[cur][0];
#pragma unroll
    for (int sl = 0; sl < 4; ++sl) {
      int K0 = sl * 16;
      f16x8 v0 = *(const f16x8*)(sVb + ((lq * 128 + K0 * 2 + hi * 16) ^ ((lq & 7) << 4)));
      f16x8 v1 = *(const f16x8*)(sVb + (((32 + lq) * 128 + K0 * 2 + hi * 16) ^ ((lq & 7) << 4)));
      oacc0 = MFMA32(v0, pf[sl], oacc0);
      oacc1 = MFMA32(v1, pf[sl], oacc1);
      oaccL = MFMA32(ones, pf[sl], oaccL);
    }
    __syncthreads();
  }

  const float rinv = 1.0f / oaccL[0];
  const size_t orow = ((size_t)b * LQ + (q0w + lq)) * D_MODEL + h * DHEAD;
#pragma unroll
  for (int dh = 0; dh < 2; ++dh)
#pragma unroll
    for (int j = 0; j < 4; ++j) {
      int d0 = dh * 32 + j * 8 + hi * 4;
      f16x4 ov;
#pragma unroll
      for (int e = 0; e < 4; ++e) {
        float x = (dh ? oacc1[j * 4 + e] : oacc0[j * 4 + e]) * rinv;
        ov[e] = (f16)x;
      }
      *(f16x4*)(O16 + orow + d0) = ov;
    }
}

// ---------------- launch ----------------
// ws plan (41 MB): slab0 QHp, slab1 KHp, slab2 VTp, slab3 O16, slab4 W16, slab5 misc.
extern "C" void kernel_launch(void* const* d_in, const int* in_sizes, int n_in,
                              void* d_out, int out_size, void* d_ws, size_t ws_size,
                              hipStream_t stream) {
  (void)in_sizes; (void)n_in; (void)out_size; (void)ws_size;
  const float* q   = (const float*)d_in[0];
  const float* k   = (const float*)d_in[1];
  const float* v   = (const float*)d_in[2];
  const void*  msk = d_in[3];
  const float* Wq  = (const float*)d_in[4];
  const float* Wk  = (const float*)d_in[5];
  const float* Wv  = (const float*)d_in[6];
  const float* Wo  = (const float*)d_in[7];
  const float* rel = (const float*)d_in[8];

  char* ws = (char*)d_ws;
  const size_t SL = (size_t)8 << 20;
  f16* QHp = (f16*)(ws + 0 * SL);
  f16* KHp = (f16*)(ws + 1 * SL);
  f16* VTp = (f16*)(ws + 2 * SL);
  f16* O16 = (f16*)(ws + 3 * SL);
  f16* W16 = (f16*)(ws + 4 * SL);
  char* misc = ws + 5 * SL;
  float* BIAS = (float*)misc;
  unsigned char* M8 = (unsigned char*)(misc + (192 << 10));

  k_cvtw_prep<<<4098, 256, 0, stream>>>(Wq, Wk, Wv, Wo, W16, msk, rel, BIAS, M8);
  k_gemm_qkv<<<768, 256, 0, stream>>>(q, k, v, W16, QHp, KHp, VTp);
  k_attn<<<512, 256, 0, stream>>>(QHp, KHp, VTp, BIAS, M8, O16);
  k_gemm_o<<<512, 256, 0, stream>>>(O16, W16 + 3 * 1048576, (float*)d_out);
}